// Round 3
// baseline (247.271 us; speedup 1.0000x reference)
//
#include <hip/hip_runtime.h>

// x = (8, 64, 256, 256) fp32, k=2, stride-1 windows -> out (8, 64, 255*255) fp32.
#define H    256
#define W    256
#define HP   255
#define WP   255
#define PIX  (HP * WP)     // 65025
#define NBC  512           // 8*64
#define EPS  1e-6f
#define LN2  0.69314718055994531f

#define ROWS 17            // output rows per thread
#define RG   15            // row-groups per image (15*17 = 255 exactly)
#define TPI  (RG * 64)     // 960 threads per image (64 col-groups of 4)
#define NBLK (TPI * NBC / 256)  // 1920 blocks, exact

typedef float f4 __attribute__((ext_vector_type(4)));
typedef f4 uf4 __attribute__((aligned(4)));   // 4B-aligned vec4 (out rows stride 255)

// Entropy of 2x2 windows, factored form:
//   ent = -sum p*ln(p+eps), p = w/s, s = sum(w)+eps
//       = ln2 * ( W*log2(s) - T ) / s,  W = sum w,  T = sum w*log2(w+eps)
// (uses ln(w+eps) ~= ln(w+eps*s); error << threshold for uniform inputs)
__global__ __launch_bounds__(256) void entropy_k2_kernel(
    const float* __restrict__ x, float* __restrict__ out)
{
    const int t  = blockIdx.x * 256 + threadIdx.x;
    const int bc = t / TPI;             // constant div -> mul_hi magic
    const int r  = t - bc * TPI;        // 0..959; wave-aligned within image
    const int i0 = (r >> 6) * ROWS;     // first output row of this thread
    const int j0 = (r & 63) << 2;       // col group: 0,4,...,252

    const float* img   = x   + (size_t)bc * (H * W);
    float*       obase = out + (size_t)bc * PIX + j0;

    // 5th column: clamp for j0==252 (its m=3 window is invalid anyway)
    const int j4 = (j0 + 4 < W) ? 4 : 3;
    const bool full = (j0 != 252);

    float phw0, phw1, phw2, phw3;   // previous row horizontal pair-sums of w
    float pht0, pht1, pht2, pht3;   // ... of w*log2(w+eps)

#pragma unroll 2
    for (int rr = 0; rr <= ROWS; ++rr) {
        const int i = i0 + rr;                       // input row, <= 255 always
        const float* row = img + i * W + j0;
        const f4    v  = *(const f4*)row;            // 16B-aligned
        const float a4 = row[j4];

        const float a0 = v.x, a1 = v.y, a2 = v.z, a3 = v.w;
        const float l0 = a0 * __builtin_amdgcn_logf(a0 + EPS);  // v_log_f32 = log2
        const float l1 = a1 * __builtin_amdgcn_logf(a1 + EPS);
        const float l2 = a2 * __builtin_amdgcn_logf(a2 + EPS);
        const float l3 = a3 * __builtin_amdgcn_logf(a3 + EPS);
        const float l4 = a4 * __builtin_amdgcn_logf(a4 + EPS);

        const float hw0 = a0 + a1, hw1 = a1 + a2, hw2 = a2 + a3, hw3 = a3 + a4;
        const float ht0 = l0 + l1, ht1 = l1 + l2, ht2 = l2 + l3, ht3 = l3 + l4;

        if (rr > 0) {
            f4 e;
            {
                const float Wm = phw0 + hw0, Tm = pht0 + ht0;
                const float s = Wm + EPS, rs = __builtin_amdgcn_rcpf(s);
                e.x = LN2 * (Wm * __builtin_amdgcn_logf(s) - Tm) * rs;
            }
            {
                const float Wm = phw1 + hw1, Tm = pht1 + ht1;
                const float s = Wm + EPS, rs = __builtin_amdgcn_rcpf(s);
                e.y = LN2 * (Wm * __builtin_amdgcn_logf(s) - Tm) * rs;
            }
            {
                const float Wm = phw2 + hw2, Tm = pht2 + ht2;
                const float s = Wm + EPS, rs = __builtin_amdgcn_rcpf(s);
                e.z = LN2 * (Wm * __builtin_amdgcn_logf(s) - Tm) * rs;
            }
            {
                const float Wm = phw3 + hw3, Tm = pht3 + ht3;
                const float s = Wm + EPS, rs = __builtin_amdgcn_rcpf(s);
                e.w = LN2 * (Wm * __builtin_amdgcn_logf(s) - Tm) * rs;
            }
            float* o = obase + (size_t)(i - 1) * WP;
            if (full) {
                *(uf4*)o = e;            // global_store_dwordx4, align 4
            } else {
                o[0] = e.x; o[1] = e.y; o[2] = e.z;
            }
        }
        phw0 = hw0; phw1 = hw1; phw2 = hw2; phw3 = hw3;
        pht0 = ht0; pht1 = ht1; pht2 = ht2; pht3 = ht3;
    }
}

extern "C" void kernel_launch(void* const* d_in, const int* in_sizes, int n_in,
                              void* d_out, int out_size, void* d_ws, size_t ws_size,
                              hipStream_t stream)
{
    const float* x   = (const float*)d_in[0];
    float*       out = (float*)d_out;
    entropy_k2_kernel<<<dim3(NBLK), 256, 0, stream>>>(x, out);
}

// Round 4
// 227.485 us; speedup vs baseline: 1.0870x; 1.0870x over previous
//
#include <hip/hip_runtime.h>

// x = (8, 64, 256, 256) fp32, k=2, stride-1 windows -> out (8, 64, 255*255) fp32.
#define H    256
#define W    256
#define HP   255
#define WP   255
#define PIX  (HP * WP)     // 65025
#define NBC  512           // 8*64
#define EPS  1e-6f
#define LN2  0.69314718055994531f

// One thread = 2 output rows x 4 cols = 8 outputs.
// Per image: 128 row-pairs x 64 col-groups = 8192 threads (power of two!).
#define TPI   8192
#define NBLK  (NBC * TPI / 256)   // 16384 blocks

typedef float f4 __attribute__((ext_vector_type(4)));

__device__ __forceinline__ float wlog(float w) {
    // w * log2(w + eps), single v_log_f32
    return w * __builtin_amdgcn_logf(w + EPS);
}

__device__ __forceinline__ float ent4(float Wm, float Tm) {
    // entropy = ln2 * (W*log2(W+eps) - T) / (W+eps)
    const float s = Wm + EPS;
    return LN2 * (Wm * __builtin_amdgcn_logf(s) - Tm) * __builtin_amdgcn_rcpf(s);
}

__global__ __launch_bounds__(256) void entropy_k2_kernel(
    const float* __restrict__ x, float* __restrict__ out)
{
    const int t  = blockIdx.x * 256 + threadIdx.x;
    const int bc = t >> 13;             // / 8192
    const int r  = t & (TPI - 1);
    const int q  = r >> 6;              // row-pair 0..127
    const int j0 = (r & 63) << 2;       // col group 0,4,...,252
    const int i0 = q << 1;              // first output row (0,2,...,254)

    const float* img = x + (size_t)bc * (H * W);
    const float* r0p = img + i0 * W + j0;
    const float* r1p = r0p + W;
    // third input row: clamp for q==127 (i0+2 == 256 doesn't exist; its
    // outputs are masked below)
    const float* r2p = (q == 127) ? r1p : r1p + W;
    // 5th column: clamp for j0==252 (its m=3 window is invalid anyway)
    const int j4 = (j0 + 4 < W) ? 4 : 3;

    // issue all 6 loads up-front (independent -> 6-deep MLP)
    const f4    va = *(const f4*)r0p;
    const f4    vb = *(const f4*)r1p;
    const f4    vc = *(const f4*)r2p;
    const float a4 = r0p[j4];
    const float b4 = r1p[j4];
    const float c4 = r2p[j4];

    // per-input logs (shared across windows)
    const float la0 = wlog(va.x), la1 = wlog(va.y), la2 = wlog(va.z),
                la3 = wlog(va.w), la4 = wlog(a4);
    const float lb0 = wlog(vb.x), lb1 = wlog(vb.y), lb2 = wlog(vb.z),
                lb3 = wlog(vb.w), lb4 = wlog(b4);
    const float lc0 = wlog(vc.x), lc1 = wlog(vc.y), lc2 = wlog(vc.z),
                lc3 = wlog(vc.w), lc4 = wlog(c4);

    // horizontal pair sums
    const float hwa0 = va.x + va.y, hwa1 = va.y + va.z, hwa2 = va.z + va.w, hwa3 = va.w + a4;
    const float hwb0 = vb.x + vb.y, hwb1 = vb.y + vb.z, hwb2 = vb.z + vb.w, hwb3 = vb.w + b4;
    const float hwc0 = vc.x + vc.y, hwc1 = vc.y + vc.z, hwc2 = vc.z + vc.w, hwc3 = vc.w + c4;
    const float hta0 = la0 + la1, hta1 = la1 + la2, hta2 = la2 + la3, hta3 = la3 + la4;
    const float htb0 = lb0 + lb1, htb1 = lb1 + lb2, htb2 = lb2 + lb3, htb3 = lb3 + lb4;
    const float htc0 = lc0 + lc1, htc1 = lc1 + lc2, htc2 = lc2 + lc3, htc3 = lc3 + lc4;

    f4 e0, e1;
    e0.x = ent4(hwa0 + hwb0, hta0 + htb0);
    e0.y = ent4(hwa1 + hwb1, hta1 + htb1);
    e0.z = ent4(hwa2 + hwb2, hta2 + htb2);
    e0.w = ent4(hwa3 + hwb3, hta3 + htb3);
    e1.x = ent4(hwb0 + hwc0, htb0 + htc0);
    e1.y = ent4(hwb1 + hwc1, htb1 + htc1);
    e1.z = ent4(hwb2 + hwc2, htb2 + htc2);
    e1.w = ent4(hwb3 + hwc3, htb3 + htc3);

    float* o0 = out + (size_t)bc * PIX + i0 * WP + j0;
    float* o1 = o0 + WP;
    const bool full = (j0 != 252);
    const bool row2 = (q != 127);       // second output row exists

    if (full) {
        // rows stride 255 floats -> only 4B alignment; store element-wise
        // nontemporal (write-once stream, keep L2/L3 for input reuse)
        __builtin_nontemporal_store(e0.x, o0 + 0);
        __builtin_nontemporal_store(e0.y, o0 + 1);
        __builtin_nontemporal_store(e0.z, o0 + 2);
        __builtin_nontemporal_store(e0.w, o0 + 3);
        if (row2) {
            __builtin_nontemporal_store(e1.x, o1 + 0);
            __builtin_nontemporal_store(e1.y, o1 + 1);
            __builtin_nontemporal_store(e1.z, o1 + 2);
            __builtin_nontemporal_store(e1.w, o1 + 3);
        }
    } else {
        __builtin_nontemporal_store(e0.x, o0 + 0);
        __builtin_nontemporal_store(e0.y, o0 + 1);
        __builtin_nontemporal_store(e0.z, o0 + 2);
        if (row2) {
            __builtin_nontemporal_store(e1.x, o1 + 0);
            __builtin_nontemporal_store(e1.y, o1 + 1);
            __builtin_nontemporal_store(e1.z, o1 + 2);
        }
    }
}

extern "C" void kernel_launch(void* const* d_in, const int* in_sizes, int n_in,
                              void* d_out, int out_size, void* d_ws, size_t ws_size,
                              hipStream_t stream)
{
    const float* x   = (const float*)d_in[0];
    float*       out = (float*)d_out;
    entropy_k2_kernel<<<dim3(NBLK), 256, 0, stream>>>(x, out);
}